// Round 4
// baseline (428.219 us; speedup 1.0000x reference)
//
#include <hip/hip_runtime.h>
#include <hip/hip_bf16.h>
#include <math.h>

// B=512, S=512, C=96. One 64-thread block (ONE wave) per batch chain.
// Lane l < 48 owns columns j0=2l, j1=2l+1. E=exp(T) columns live in
// registers/AGPRs as packed half2. Per step: p=exp(alpha-m)*SC packed fp16
// -> LDS (48 dwords), broadcast-read as 12 ds_read_b128, matvec via
// v_dot2_f32_f16 (fp32 accum). Lagged (1-step) centering max via DPP.
// KEY (R4): no __syncthreads() -- it drains vmcnt(0) and puts the global
// emission prefetch on the serial critical path (~900 cyc/step measured).
// Single-wave workgroup + in-order DS pipe means `s_waitcnt lgkmcnt(0)`
// with a compiler memory clobber is sufficient for the LDS exchange.

#define BATCH 512
#define SEQ   512
#define NC    96
#define NTHR  64
#define NEG_INF (-1e30f)
#define SC    0.25f                  // fp16 headroom scale
#define LSC   1.3862943611198906f    // -log(SC)

typedef __fp16 half2v __attribute__((ext_vector_type(2)));

// LDS exchange fence for a single-wave workgroup: order ds_write -> ds_read
// without draining vmcnt (keeps global prefetch in flight).
#define WAVE_LDS_FENCE() asm volatile("s_waitcnt lgkmcnt(0)" ::: "memory")

// ---- DPP wave64 reduce (result broadcast via readlane 63) -------------
#define DPP_STEP_F(v, op, ctrl)                                              \
    v = op(v, __int_as_float(__builtin_amdgcn_update_dpp(                    \
            __float_as_int(v), __float_as_int(v), (ctrl), 0xf, 0xf, false)))

__device__ __forceinline__ float wave_max_all(float v) {
    DPP_STEP_F(v, fmaxf, 0x111);  // row_shr:1
    DPP_STEP_F(v, fmaxf, 0x112);  // row_shr:2
    DPP_STEP_F(v, fmaxf, 0x114);  // row_shr:4
    DPP_STEP_F(v, fmaxf, 0x118);  // row_shr:8
    DPP_STEP_F(v, fmaxf, 0x142);  // row_bcast:15
    DPP_STEP_F(v, fmaxf, 0x143);  // row_bcast:31
    return __int_as_float(__builtin_amdgcn_readlane(__float_as_int(v), 63));
}
__device__ __forceinline__ float fadd_(float a, float b) { return a + b; }
__device__ __forceinline__ float wave_sum_all(float v) {
    DPP_STEP_F(v, fadd_, 0x111);
    DPP_STEP_F(v, fadd_, 0x112);
    DPP_STEP_F(v, fadd_, 0x114);
    DPP_STEP_F(v, fadd_, 0x118);
    DPP_STEP_F(v, fadd_, 0x142);
    DPP_STEP_F(v, fadd_, 0x143);
    return __int_as_float(__builtin_amdgcn_readlane(__float_as_int(v), 63));
}

__global__ __launch_bounds__(NTHR, 1)
void crf_llh_kernel(const float* __restrict__ em,      // (B,S,C)
                    const int*   __restrict__ tags,    // (B,S)
                    const int*   __restrict__ masks,   // (B,S)
                    const float* __restrict__ startT,  // (C)
                    const float* __restrict__ endT,    // (C)
                    const float* __restrict__ trans,   // (C,C)
                    float*       __restrict__ out)     // scalar
{
    const int b = blockIdx.x;
    const int l = threadIdx.x;            // lane 0..63
    const bool active = (l < 48);
    const int j0 = active ? 2 * l     : 0;
    const int j1 = active ? 2 * l + 1 : 0;
    const int lr = (l < 48) ? l : (l - 48);   // row index for em loads

    __shared__ __align__(16) half2v qsh[48];   // 192 B

    const float* em_b    = em    + (size_t)b * SEQ * NC;
    const int*   tags_b  = tags  + b * SEQ;
    const int*   masks_b = masks + b * SEQ;

    // ---- E columns (exp of transitions), packed half2 pairs along i ----
    half2v e0[48], e1[48];
    #pragma unroll
    for (int k = 0; k < 48; ++k) {
        const float t00 = trans[(2 * k)     * NC + j0];
        const float t01 = trans[(2 * k + 1) * NC + j0];
        const float t10 = trans[(2 * k)     * NC + j1];
        const float t11 = trans[(2 * k + 1) * NC + j1];
        e0[k] = __builtin_amdgcn_cvt_pkrtz(__expf(t00), __expf(t01));
        e1[k] = __builtin_amdgcn_cvt_pkrtz(__expf(t10), __expf(t11));
    }

    // ---- alpha0 = start + em[0]
    float a0 = active ? (startT[j0] + em_b[j0]) : NEG_INF;
    float a1 = active ? (startT[j1] + em_b[j1]) : NEG_INF;
    float m  = wave_max_all(fmaxf(a0, a1));    // exact initial max

    // ---- prefetch pipeline (distance 3) for emissions + mask
    const float2* em2 = reinterpret_cast<const float2*>(em_b);
    float2 emA = em2[1 * (NC / 2) + lr];   // step 1
    float2 emB = em2[2 * (NC / 2) + lr];   // step 2
    float2 emC = em2[3 * (NC / 2) + lr];   // step 3
    int mkA = masks_b[1];
    int mkB = masks_b[2];
    int mkC = masks_b[3];

    for (int s = 1; s < SEQ; ++s) {
        const int sp = (s + 3 < SEQ) ? (s + 3) : (SEQ - 1);
        const float2 emN = em2[sp * (NC / 2) + lr];
        const int    mkN = masks_b[sp];

        // next-step centering max (lag-1) -- VALU/DPP pipe
        const float wm = wave_max_all(fmaxf(a0, a1));

        // p = exp(alpha - m) * SC, packed fp16 -> LDS
        const float p0 = __expf(a0 - m) * SC;
        const float p1 = __expf(a1 - m) * SC;
        const half2v ph = __builtin_amdgcn_cvt_pkrtz(p0, p1);
        if (active) qsh[l] = ph;
        WAVE_LDS_FENCE();   // order write->read; do NOT drain vmcnt

        // matvec: acc_j = sum_i p_i * E[i][j] via v_dot2_f32_f16
        float acc0a = 0.f, acc0b = 0.f, acc1a = 0.f, acc1b = 0.f;
        const uint4* q4 = reinterpret_cast<const uint4*>(qsh);
        #pragma unroll
        for (int t = 0; t < 12; ++t) {
            const uint4 qv = q4[t];
            const half2v qx = __builtin_bit_cast(half2v, qv.x);
            const half2v qy = __builtin_bit_cast(half2v, qv.y);
            const half2v qz = __builtin_bit_cast(half2v, qv.z);
            const half2v qw = __builtin_bit_cast(half2v, qv.w);
            acc0a = __builtin_amdgcn_fdot2(qx, e0[4 * t + 0], acc0a, false);
            acc1a = __builtin_amdgcn_fdot2(qx, e1[4 * t + 0], acc1a, false);
            acc0a = __builtin_amdgcn_fdot2(qy, e0[4 * t + 1], acc0a, false);
            acc1a = __builtin_amdgcn_fdot2(qy, e1[4 * t + 1], acc1a, false);
            acc0b = __builtin_amdgcn_fdot2(qz, e0[4 * t + 2], acc0b, false);
            acc1b = __builtin_amdgcn_fdot2(qz, e1[4 * t + 2], acc1b, false);
            acc0b = __builtin_amdgcn_fdot2(qw, e0[4 * t + 3], acc0b, false);
            acc1b = __builtin_amdgcn_fdot2(qw, e1[4 * t + 3], acc1b, false);
        }
        const float acc0 = acc0a + acc0b;
        const float acc1 = acc1a + acc1b;

        const bool upd = active && (mkA != 0);
        const float na0 = m + __logf(acc0) + LSC + emA.x;
        const float na1 = m + __logf(acc1) + LSC + emA.y;
        a0 = upd ? na0 : a0;
        a1 = upd ? na1 : a1;
        m = wm;

        // ordering: next iteration's ds_write is issued after this
        // iteration's ds_reads in program order; the DS pipe is in-order
        // per wave, so no extra fence is needed before the overwrite.
        emA = emB; emB = emC; emC = emN;
        mkA = mkB; mkB = mkC; mkC = mkN;
    }

    // ---- denominator = logsumexp_j(alpha_j + end_j)
    const float v0 = active ? (a0 + endT[j0]) : NEG_INF;
    const float v1 = active ? (a1 + endT[j1]) : NEG_INF;
    const float M  = wave_max_all(fmaxf(v0, v1));
    const float e  = active ? (__expf(v0 - M) + __expf(v1 - M)) : 0.f;
    const float denom = M + __logf(wave_sum_all(e));

    // ---- numerator: gather along the tag path
    float nsum = 0.f;
    float msum = 0.f;
    #pragma unroll
    for (int k = 0; k < SEQ / NTHR; ++k) {
        const int s  = l + NTHR * k;
        const int tg = tags_b[s];
        const int mk = masks_b[s];
        msum += (mk ? 1.f : 0.f);
        if (s == 0) {
            nsum += startT[tg] + em_b[tg];
        } else if (mk) {
            nsum += trans[tags_b[s - 1] * NC + tg] + em_b[s * NC + tg];
        }
    }
    nsum = wave_sum_all(nsum);
    msum = wave_sum_all(msum);
    if (l == 0) {
        const int cnt  = (int)msum;
        const int last = tags_b[cnt - 1];
        atomicAdd(out, (nsum + endT[last] - denom) * (1.0f / (float)BATCH));
    }
}

extern "C" void kernel_launch(void* const* d_in, const int* in_sizes, int n_in,
                              void* d_out, int out_size, void* d_ws, size_t ws_size,
                              hipStream_t stream) {
    const float* em     = (const float*)d_in[0];
    const int*   tags   = (const int*)  d_in[1];
    const int*   masks  = (const int*)  d_in[2];
    const float* startT = (const float*)d_in[3];
    const float* endT   = (const float*)d_in[4];
    const float* trans  = (const float*)d_in[5];
    float* out = (float*)d_out;

    (void)hipMemsetAsync(out, 0, sizeof(float), stream);
    crf_llh_kernel<<<BATCH, NTHR, 0, stream>>>(em, tags, masks, startT, endT, trans, out);
}

// Round 6
// 403.413 us; speedup vs baseline: 1.0615x; 1.0615x over previous
//
#include <hip/hip_runtime.h>
#include <hip/hip_bf16.h>
#include <math.h>

// B=512, S=512, C=96. One block (2 waves, 128 thr) per chain; thread j<96
// owns column j; E=exp(T) column = 48 half2 VGPRs/lane. State = UNNORMALIZED
// scaled probs w (fp16 in LDS, bounded by construction); the exact exponent
// K of max(w) travels through the SAME barrier and is folded into the next
// step's dot result via ldexp -- per-step EXACT power-of-2 normalization,
// no lag-1 feedback (R5's lag-1 scheme resonated: x^2-x+1 roots on unit
// circle -> fp16 overflow -> NaN). exp/log stay off the critical path;
// log-scale accumulates as an exact integer exponent sum. Barriers are
// lgkm-only (global emission prefetch stays in flight).

#define BATCH 512
#define SEQ   512
#define NC    96
#define NTHR  128
#define LN2   0.69314718055994531f

typedef __fp16 half2v __attribute__((ext_vector_type(2)));

// barrier that does NOT drain vmcnt (keeps emission prefetch in flight)
#define BARRIER() asm volatile("s_waitcnt lgkmcnt(0)\n\ts_barrier" ::: "memory")

// ---- DPP wave64 reduce (result broadcast via readlane 63) -------------
#define DPP_STEP_F(v, op, ctrl)                                              \
    v = op(v, __int_as_float(__builtin_amdgcn_update_dpp(                    \
            __float_as_int(v), __float_as_int(v), (ctrl), 0xf, 0xf, false)))

__device__ __forceinline__ float wave_max_all(float v) {
    DPP_STEP_F(v, fmaxf, 0x111);
    DPP_STEP_F(v, fmaxf, 0x112);
    DPP_STEP_F(v, fmaxf, 0x114);
    DPP_STEP_F(v, fmaxf, 0x118);
    DPP_STEP_F(v, fmaxf, 0x142);
    DPP_STEP_F(v, fmaxf, 0x143);
    return __int_as_float(__builtin_amdgcn_readlane(__float_as_int(v), 63));
}
__device__ __forceinline__ float fadd_(float a, float b) { return a + b; }
__device__ __forceinline__ float wave_sum_all(float v) {
    DPP_STEP_F(v, fadd_, 0x111);
    DPP_STEP_F(v, fadd_, 0x112);
    DPP_STEP_F(v, fadd_, 0x114);
    DPP_STEP_F(v, fadd_, 0x118);
    DPP_STEP_F(v, fadd_, 0x142);
    DPP_STEP_F(v, fadd_, 0x143);
    return __int_as_float(__builtin_amdgcn_readlane(__float_as_int(v), 63));
}

__global__ __launch_bounds__(NTHR, 1)
void crf_llh_kernel(const float* __restrict__ em,      // (B,S,C)
                    const int*   __restrict__ tags,    // (B,S)
                    const int*   __restrict__ masks,   // (B,S)
                    const float* __restrict__ startT,  // (C)
                    const float* __restrict__ endT,    // (C)
                    const float* __restrict__ trans,   // (C,C)
                    float*       __restrict__ out)     // scalar
{
    const int b    = blockIdx.x;
    const int tid  = threadIdx.x;     // 0..127; column index
    const int lane = tid & 63;
    const int wid  = tid >> 6;
    const bool active = (tid < NC);
    const int jc = active ? tid : 0;

    __shared__ __align__(16) __fp16 qsh[2][128];  // double-buffered state (w)
    __shared__ float maxsh[2][2];                 // [parity][wave]
    __shared__ float redn[2], redm[2], redd[2];

    const float* em_b    = em    + (size_t)b * SEQ * NC;
    const int*   tags_b  = tags  + b * SEQ;
    const int*   masks_b = masks + b * SEQ;

    // ---- E column jc as 48 half2 (pairs along i) — 48 VGPRs
    half2v ecol[48];
    #pragma unroll
    for (int k = 0; k < 48; ++k) {
        ecol[k] = __builtin_amdgcn_cvt_pkrtz(
            __expf(trans[(2 * k)     * NC + jc]),
            __expf(trans[(2 * k + 1) * NC + jc]));
    }

    // ---- init: alpha0 = start + em[0]; M0 = exact block max
    const float al0 = startT[jc] + em_b[jc];
    {
        const float wm = wave_max_all(active ? al0 : -1e30f);
        if (lane == 0) maxsh[0][wid] = wm;
    }
    BARRIER();
    const float M0 = fmaxf(maxsh[0][0], maxsh[0][1]);
    float wreg = active ? __expf(al0 - M0) : 0.f;   // max(wreg) == 1.0
    qsh[1][tid] = (__fp16)wreg;                     // step 1 reads buffer 1
    BARRIER();

    int K    = 1;   // exponent of max(w) currently in qsh: 1.0 in [2^0,2^1)
    int sumk = 0;   // exact accumulated exponent

    // ---- prefetch pipeline (distance 3)
    float emA = em_b[1 * NC + jc];
    float emB = em_b[2 * NC + jc];
    float emC = em_b[3 * NC + jc];
    int mkA = masks_b[1], mkB = masks_b[2], mkC = masks_b[3];

    for (int s = 1; s < SEQ; ++s) {
        const int rb = s & 1;
        const int sp = (s + 3 < SEQ) ? (s + 3) : (SEQ - 1);
        const float emN = em_b[sp * NC + jc];
        const int   mkN = masks_b[sp];

        // load ALL 12 q-vectors first (keeps 12 ds_read_b128 in flight)
        const uint4* q4p = reinterpret_cast<const uint4*>(&qsh[rb][0]);
        uint4 qv[12];
        #pragma unroll
        for (int t = 0; t < 12; ++t) qv[t] = q4p[t];

        // dot: U_j = sum_i w_i * E[i][jc]  (48 fdot2, 6 indep chains)
        float acc[6] = {0.f, 0.f, 0.f, 0.f, 0.f, 0.f};
        #pragma unroll
        for (int t = 0; t < 12; ++t) {
            const half2v qx = __builtin_bit_cast(half2v, qv[t].x);
            const half2v qy = __builtin_bit_cast(half2v, qv[t].y);
            const half2v qz = __builtin_bit_cast(half2v, qv[t].z);
            const half2v qw = __builtin_bit_cast(half2v, qv[t].w);
            acc[(4 * t + 0) % 6] = __builtin_amdgcn_fdot2(qx, ecol[4 * t + 0], acc[(4 * t + 0) % 6], false);
            acc[(4 * t + 1) % 6] = __builtin_amdgcn_fdot2(qy, ecol[4 * t + 1], acc[(4 * t + 1) % 6], false);
            acc[(4 * t + 2) % 6] = __builtin_amdgcn_fdot2(qz, ecol[4 * t + 2], acc[(4 * t + 2) % 6], false);
            acc[(4 * t + 3) % 6] = __builtin_amdgcn_fdot2(qw, ecol[4 * t + 3], acc[(4 * t + 3) % 6], false);
        }
        const float U = ((acc[0] + acc[1]) + (acc[2] + acc[3])) + (acc[4] + acc[5]);

        // exact normalization by the CURRENT buffer's max exponent (K),
        // then multiply by exp(em) (computed off-path from the prefetch)
        const float F = __expf(emA);
        float w = ldexpf(U, -(K + 6)) * F;   // bounded: u<=1.66, w<=1.66*e^|em|
        if (!active) w = 0.f;
        w = mkA ? w : wreg;                  // masked step: state unchanged
        sumk += mkA ? (K + 6) : 0;
        wreg = w;

        const float wmx = wave_max_all(w);
        if (lane == 0) maxsh[rb][wid] = wmx;
        qsh[rb ^ 1][tid] = (__fp16)w;
        BARRIER();

        // exponent of the exact max of the values just written (for s+1)
        const float r = fmaxf(maxsh[rb][0], maxsh[rb][1]);
        K = (int)((__float_as_uint(r) >> 23) & 255u) - 126;

        emA = emB; emB = emC; emC = emN;
        mkA = mkB; mkB = mkC; mkC = mkN;
    }

    // ---- denominator = M0 + sumk*ln2 + log(sum_j w_j * exp(end_j))
    const float dv = active ? wreg * __expf(endT[jc]) : 0.f;
    {
        const float ws = wave_sum_all(dv);
        if (lane == 0) redd[wid] = ws;
    }
    __syncthreads();
    const float denom = M0 + (float)sumk * LN2 + __logf(redd[0] + redd[1]);

    // ---- numerator: gather along the tag path (128 threads, 4 steps each)
    float nsum = 0.f, msum = 0.f;
    #pragma unroll
    for (int kk = 0; kk < SEQ / NTHR; ++kk) {
        const int s  = tid + NTHR * kk;
        const int tg = tags_b[s];
        const int mk = masks_b[s];
        msum += mk ? 1.f : 0.f;
        if (s == 0) {
            nsum += startT[tg] + em_b[tg];
        } else if (mk) {
            nsum += trans[tags_b[s - 1] * NC + tg] + em_b[s * NC + tg];
        }
    }
    nsum = wave_sum_all(nsum);
    msum = wave_sum_all(msum);
    if (lane == 0) { redn[wid] = nsum; redm[wid] = msum; }
    __syncthreads();
    if (tid == 0) {
        const float numer = redn[0] + redn[1];
        const int   cnt   = (int)(redm[0] + redm[1]);
        const int   last  = tags_b[cnt - 1];
        atomicAdd(out, (numer + endT[last] - denom) * (1.0f / (float)BATCH));
    }
}

extern "C" void kernel_launch(void* const* d_in, const int* in_sizes, int n_in,
                              void* d_out, int out_size, void* d_ws, size_t ws_size,
                              hipStream_t stream) {
    const float* em     = (const float*)d_in[0];
    const int*   tags   = (const int*)  d_in[1];
    const int*   masks  = (const int*)  d_in[2];
    const float* startT = (const float*)d_in[3];
    const float* endT   = (const float*)d_in[4];
    const float* trans  = (const float*)d_in[5];
    float* out = (float*)d_out;

    (void)hipMemsetAsync(out, 0, sizeof(float), stream);
    crf_llh_kernel<<<BATCH, NTHR, 0, stream>>>(em, tags, masks, startT, endT, trans, out);
}